// Round 4
// baseline (7271.027 us; speedup 1.0000x reference)
//
#include <hip/hip_runtime.h>

#define T_DIM 512
#define B_DIM 64
#define F_DIM 128
#define H_DIM 512

typedef _Float16 f16x8 __attribute__((ext_vector_type(8)));
typedef float f32x4 __attribute__((ext_vector_type(4)));

// ---------------------------------------------------------------------------
// prep: whT16[l][j][k] f16  (wh[k][j] transposed, for B-fragment loads)
// ---------------------------------------------------------------------------
__global__ void prep_whT16(_Float16* __restrict__ dst, const float* __restrict__ w0,
                           const float* __restrict__ w1, const float* __restrict__ w2) {
  const long total = 3L * 512 * 512;
  for (long idx = (long)blockIdx.x * blockDim.x + threadIdx.x; idx < total;
       idx += (long)gridDim.x * blockDim.x) {
    int l = (int)(idx >> 18);
    int rem = (int)(idx & 262143);
    int j = rem >> 9, k = rem & 511;
    const float* src = (l == 0) ? w0 : (l == 1) ? w1 : w2;
    dst[idx] = (_Float16)src[k * 512 + j];
  }
}

// ---------------------------------------------------------------------------
// prep: Wcat^T [l][n=512][kc=640] f16
// ---------------------------------------------------------------------------
__global__ void prep_wcat(_Float16* __restrict__ dst,
                          const float* __restrict__ wi0, const float* __restrict__ ws0,
                          const float* __restrict__ wi1, const float* __restrict__ ws1,
                          const float* __restrict__ wi2, const float* __restrict__ ws2) {
  const long total = 3L * 512 * 640;
  for (long idx = (long)blockIdx.x * blockDim.x + threadIdx.x; idx < total;
       idx += (long)gridDim.x * blockDim.x) {
    int l = (int)(idx / 327680);
    int rem = (int)(idx % 327680);
    int n = rem / 640, kc = rem % 640;
    int inK = (l == 0) ? 128 : 512;
    const float* wi = (l == 0) ? wi0 : (l == 1) ? wi1 : wi2;
    const float* ws = (l == 0) ? ws0 : (l == 1) ? ws1 : ws2;
    float v = 0.f;
    if (kc < inK) v = wi[kc * 512 + n];
    else if (kc < inK + 128) v = ws[(kc - inK) * 512 + n];
    dst[idx] = (_Float16)v;
  }
}

// ---------------------------------------------------------------------------
// build A' panel f16 (unchanged, verified)
// ---------------------------------------------------------------------------
__global__ void build_A(_Float16* __restrict__ Abuf, const float* __restrict__ xin,
                        const float* __restrict__ prev, int n, int inK, int scale,
                        int layer) {
  const int Kcat = inK + 128;
  const long total = (long)n * 64 * Kcat;
  for (long idx = (long)blockIdx.x * blockDim.x + threadIdx.x; idx < total;
       idx += (long)gridDim.x * blockDim.x) {
    int k = (int)(idx % Kcat);
    long r = idx / Kcat;
    int b = (int)(r & 63);
    int t = (int)(r >> 6);
    float v;
    if (k < inK) {
      if (layer == 0) v = xin[((long)b * T_DIM + t) * F_DIM + k];
      else v = prev[((long)(t + scale - 1) * B_DIM + b) * H_DIM + k];
    } else {
      int kk = k - inK;
      int t0 = t + scale - 1;
      float s = 0.f;
      for (int w = 0; w < scale; ++w) s += xin[((long)b * T_DIM + t0 + w) * F_DIM + kk];
      v = s * (1.f / scale);
    }
    Abuf[idx] = (_Float16)v;
  }
}

// ---------------------------------------------------------------------------
// f16 MFMA GEMM (unchanged, verified)
// ---------------------------------------------------------------------------
__global__ __launch_bounds__(256) void gemm_f16(const _Float16* __restrict__ A,
                                                const _Float16* __restrict__ Bt,
                                                float* __restrict__ C, int Mrows,
                                                int Kcat) {
  __shared__ _Float16 As[128][72];
  __shared__ _Float16 Bs[128][72];
  const int tid = threadIdx.x;
  const int tn = blockIdx.x, tm = blockIdx.y;
  const int lane = tid & 63, wid = tid >> 6;
  const int wm = wid >> 1, wn = wid & 1;
  f32x4 acc[4][4] = {};
  const int nK = Kcat >> 6;
  const int lrow = tid >> 3, lkc = (tid & 7) * 8;

  for (int kt = 0; kt < nK; ++kt) {
    for (int r = 0; r < 4; ++r) {
      int row = r * 32 + lrow;
      int grow = tm * 128 + row;
      uint4 va = make_uint4(0u, 0u, 0u, 0u);
      if (grow < Mrows) va = *(const uint4*)&A[(size_t)grow * Kcat + kt * 64 + lkc];
      *(uint4*)&As[row][lkc] = va;
      uint4 vb = *(const uint4*)&Bt[(size_t)(tn * 128 + row) * 640 + kt * 64 + lkc];
      *(uint4*)&Bs[row][lkc] = vb;
    }
    __syncthreads();
#pragma unroll
    for (int kk = 0; kk < 64; kk += 32) {
      f16x8 af[4], bf[4];
#pragma unroll
      for (int mt = 0; mt < 4; ++mt)
        af[mt] = *(const f16x8*)&As[wm * 64 + mt * 16 + (lane & 15)][kk + (lane >> 4) * 8];
#pragma unroll
      for (int nt = 0; nt < 4; ++nt)
        bf[nt] = *(const f16x8*)&Bs[wn * 64 + nt * 16 + (lane & 15)][kk + (lane >> 4) * 8];
#pragma unroll
      for (int mt = 0; mt < 4; ++mt)
#pragma unroll
        for (int nt = 0; nt < 4; ++nt)
          acc[mt][nt] = __builtin_amdgcn_mfma_f32_16x16x32_f16(af[mt], bf[nt], acc[mt][nt], 0, 0, 0);
    }
    __syncthreads();
  }

  const int crow0 = tm * 128 + wm * 64 + (lane >> 4) * 4;
  const int ccol0 = tn * 128 + wn * 64 + (lane & 15);
#pragma unroll
  for (int mt = 0; mt < 4; ++mt)
#pragma unroll
    for (int q = 0; q < 4; ++q) {
      int grow = crow0 + mt * 16 + q;
      if (grow < Mrows) {
#pragma unroll
        for (int nt = 0; nt < 4; ++nt)
          C[(size_t)grow * 512 + ccol0 + nt * 16] = acc[mt][nt][q];
      }
    }
}

// ---------------------------------------------------------------------------
// rec_fused v2: 4 WGs x 256 thr (1 wave/SIMD). wh: kb 0..11 in VGPR/AGPR
// (bfr[8][12]), kb 12..15 in LDS (128 KB frag-order). h exchanged via
// DOUBLE-BUFFERED XOR-swizzled LDS hstage with ONE raw s_barrier per step
// (lgkmcnt-only drain -> global loads/stores stream across steps).
// hstage element (b,j) at f16 index b*512 + (j ^ ((b&7)<<3)).
// ---------------------------------------------------------------------------
__global__ __launch_bounds__(256, 1) void rec_fused(float* __restrict__ po,
                                                    const _Float16* __restrict__ whT,
                                                    int n) {
  const int tid = threadIdx.x;
  const int b0g = blockIdx.x * 16;
  const int lane = tid & 63, wid = tid >> 6;
  const int colbase = wid * 128;  // wave owns cols [128w, 128w+128)
  const int q_col = lane & 15;
  const int q_row = (lane >> 4) * 4;

  __shared__ _Float16 hstage[2][16 * 512];     // 32 KB, XOR-swizzled [b][j]
  __shared__ _Float16 Blds[4 * 32 * 64 * 8];   // 128 KB, B-frag order kb 12..15

  // one-time: fill Blds (frag-order gather from whT)
  {
    uint4* B4 = (uint4*)Blds;
    for (int p = 0; p < 32; ++p) {
      int flat = p * 256 + tid;          // 0..8191
      int l = flat & 63;
      int gn = (flat >> 6) & 31;
      int kb12 = flat >> 11;             // 0..3
      B4[flat] = *(const uint4*)&whT[(size_t)(gn * 16 + (l & 15)) * 512 +
                                     (kb12 + 12) * 32 + (l >> 4) * 8];
    }
  }
  // one-time: B-frags kb 0..11 (8 n-tiles x 12 kb = 384 regs, VGPR+AGPR)
  f16x8 bfr[8][12];
  {
    const int ko = (lane >> 4) * 8;
#pragma unroll
    for (int nt = 0; nt < 8; ++nt) {
      const int j = colbase + nt * 16 + q_col;
#pragma unroll
      for (int kb = 0; kb < 12; ++kb)
        bfr[nt][kb] = *(const f16x8*)&whT[(size_t)j * 512 + kb * 32 + ko];
    }
  }
  __syncthreads();  // Blds ready

  // A-frag read base for this lane: b = lane&15, j0 = kb*32 + (lane>>4)*8
  const int rd_b = lane & 15;
  const int rd_swz = (lane & 7) << 3;
  const int rd_base = rd_b * 512;
  const int rd_j0 = (lane >> 4) * 8;

  // global element (nt,q): po[t*32768 + (b0g+q_row+q)*512 + colbase+nt*16+q_col]
  const size_t base = (size_t)(b0g + q_row) * 512 + colbase + q_col;

  // write indices into hstage (per nt,q): (q_row+q)*512 + (j ^ ((b&7)<<3))
  // prefetch pre[0]
  float pf[8][4];
  {
    const float* p0 = po + base;
#pragma unroll
    for (int nt = 0; nt < 8; ++nt)
#pragma unroll
      for (int q = 0; q < 4; ++q) pf[nt][q] = p0[q * 512 + nt * 16];
  }

  for (int t = 0; t < n; ++t) {
    f32x4 acc[8];
#pragma unroll
    for (int nt = 0; nt < 8; ++nt) {
      acc[nt][0] = pf[nt][0];
      acc[nt][1] = pf[nt][1];
      acc[nt][2] = pf[nt][2];
      acc[nt][3] = pf[nt][3];
    }
    // issue prefetch pre[t+1] (hides under MFMA; never drained by barrier)
    {
      const int tnx = (t + 1 < n) ? t + 1 : t;
      const float* pn = po + (size_t)tnx * (B_DIM * H_DIM) + base;
#pragma unroll
      for (int nt = 0; nt < 8; ++nt)
#pragma unroll
        for (int q = 0; q < 4; ++q) pf[nt][q] = pn[q * 512 + nt * 16];
    }

    if (t > 0) {
      const _Float16* hs = hstage[(t - 1) & 1];
      // kb 0..11: B from registers
#pragma unroll
      for (int kb = 0; kb < 12; ++kb) {
        f16x8 af = *(const f16x8*)&hs[rd_base + ((kb * 32 + rd_j0) ^ rd_swz)];
#pragma unroll
        for (int nt = 0; nt < 8; ++nt)
          acc[nt] = __builtin_amdgcn_mfma_f32_16x16x32_f16(af, bfr[nt][kb], acc[nt], 0, 0, 0);
      }
      // kb 12..15: B from LDS
#pragma unroll
      for (int kb = 12; kb < 16; ++kb) {
        f16x8 af = *(const f16x8*)&hs[rd_base + ((kb * 32 + rd_j0) ^ rd_swz)];
#pragma unroll
        for (int nt = 0; nt < 8; ++nt) {
          const int gn = (colbase >> 4) + nt;
          f16x8 bl = *(const f16x8*)&Blds[(((kb - 12) * 32 + gn) * 64 + lane) * 8];
          acc[nt] = __builtin_amdgcn_mfma_f32_16x16x32_f16(af, bl, acc[nt], 0, 0, 0);
        }
      }
    }

    // tanh; write h16 to hstage slot t&1 (swizzled); write f32 out (fire&forget)
    _Float16* hw = hstage[t & 1];
    float* pw = po + (size_t)t * (B_DIM * H_DIM) + base;
#pragma unroll
    for (int nt = 0; nt < 8; ++nt) {
      const int j0 = colbase + nt * 16 + q_col;
#pragma unroll
      for (int q = 0; q < 4; ++q) {
        const int b = q_row + q;
        float a = acc[nt][q];
        float e = __expf(2.f * a);
        float h = 1.f - 2.f / (e + 1.f);
        hw[b * 512 + (j0 ^ ((b & 7) << 3))] = (_Float16)h;
        pw[q * 512 + nt * 16] = h;
      }
    }
    // single barrier: drain LDS writes only (no vmcnt drain!)
    asm volatile("s_waitcnt lgkmcnt(0)\n\ts_barrier" ::: "memory");
  }
}

// ---------------------------------------------------------------------------
extern "C" void kernel_launch(void* const* d_in, const int* in_sizes, int n_in,
                              void* d_out, int out_size, void* d_ws, size_t ws_size,
                              hipStream_t stream) {
  const float* inputs = (const float*)d_in[0];
  const float* wi[3] = {(const float*)d_in[1], (const float*)d_in[4], (const float*)d_in[7]};
  const float* wsm[3] = {(const float*)d_in[2], (const float*)d_in[5], (const float*)d_in[8]};
  const float* wh[3] = {(const float*)d_in[3], (const float*)d_in[6], (const float*)d_in[9]};
  float* out = (float*)d_out;

  char* wsp = (char*)d_ws;
  _Float16* whT16 = (_Float16*)wsp;                 // 3*512*512*2 = 1,572,864
  _Float16* wcat = (_Float16*)(wsp + 1572864);      // 3*512*640*2 = 1,966,080
  _Float16* Abuf = (_Float16*)(wsp + 3538944);      // 32704*640*2 = 41,861,120

  prep_whT16<<<1024, 256, 0, stream>>>(whT16, wh[0], wh[1], wh[2]);
  prep_wcat<<<1024, 256, 0, stream>>>(wcat, wi[0], wsm[0], wi[1], wsm[1], wi[2], wsm[2]);

  const int nL[3] = {511, 509, 505};
  const long offL[3] = {0L, 511L * 64 * 512, (511L + 509L) * 64 * 512};
  const int inKL[3] = {128, 512, 512};
  const int scaleL[3] = {1, 2, 4};

  for (int l = 0; l < 3; ++l) {
    const int n = nL[l], inK = inKL[l], Kcat = inK + 128;
    const float* prev = (l == 0) ? nullptr : out + offL[l - 1];
    build_A<<<4096, 256, 0, stream>>>(Abuf, inputs, prev, n, inK, scaleL[l], l);
    const int Mrows = n * 64;
    const int Mt = (Mrows + 127) / 128;
    gemm_f16<<<dim3(4, Mt), 256, 0, stream>>>(Abuf, wcat + (size_t)l * 512 * 640,
                                              out + offL[l], Mrows, Kcat);
    rec_fused<<<4, 256, 0, stream>>>(out + offL[l], whT16 + (size_t)l * 262144, n);
  }
}

// Round 5
// 4736.954 us; speedup vs baseline: 1.5350x; 1.5350x over previous
//
#include <hip/hip_runtime.h>

#define T_DIM 512
#define B_DIM 64
#define F_DIM 128
#define H_DIM 512

typedef _Float16 f16x8 __attribute__((ext_vector_type(8)));
typedef _Float16 f16x4 __attribute__((ext_vector_type(4)));
typedef float f32x4 __attribute__((ext_vector_type(4)));

// ---------------------------------------------------------------------------
// prep: whT16[l][j][k] f16  (wh[k][j] transposed, for A-fragment loads)
// ---------------------------------------------------------------------------
__global__ void prep_whT16(_Float16* __restrict__ dst, const float* __restrict__ w0,
                           const float* __restrict__ w1, const float* __restrict__ w2) {
  const long total = 3L * 512 * 512;
  for (long idx = (long)blockIdx.x * blockDim.x + threadIdx.x; idx < total;
       idx += (long)gridDim.x * blockDim.x) {
    int l = (int)(idx >> 18);
    int rem = (int)(idx & 262143);
    int j = rem >> 9, k = rem & 511;
    const float* src = (l == 0) ? w0 : (l == 1) ? w1 : w2;
    dst[idx] = (_Float16)src[k * 512 + j];
  }
}

// ---------------------------------------------------------------------------
// prep: Wcat^T [l][n=512][kc=640] f16
// ---------------------------------------------------------------------------
__global__ void prep_wcat(_Float16* __restrict__ dst,
                          const float* __restrict__ wi0, const float* __restrict__ ws0,
                          const float* __restrict__ wi1, const float* __restrict__ ws1,
                          const float* __restrict__ wi2, const float* __restrict__ ws2) {
  const long total = 3L * 512 * 640;
  for (long idx = (long)blockIdx.x * blockDim.x + threadIdx.x; idx < total;
       idx += (long)gridDim.x * blockDim.x) {
    int l = (int)(idx / 327680);
    int rem = (int)(idx % 327680);
    int n = rem / 640, kc = rem % 640;
    int inK = (l == 0) ? 128 : 512;
    const float* wi = (l == 0) ? wi0 : (l == 1) ? wi1 : wi2;
    const float* ws = (l == 0) ? ws0 : (l == 1) ? ws1 : ws2;
    float v = 0.f;
    if (kc < inK) v = wi[kc * 512 + n];
    else if (kc < inK + 128) v = ws[(kc - inK) * 512 + n];
    dst[idx] = (_Float16)v;
  }
}

// ---------------------------------------------------------------------------
// build A' panel f16 (unchanged, verified)
// ---------------------------------------------------------------------------
__global__ void build_A(_Float16* __restrict__ Abuf, const float* __restrict__ xin,
                        const float* __restrict__ prev, int n, int inK, int scale,
                        int layer) {
  const int Kcat = inK + 128;
  const long total = (long)n * 64 * Kcat;
  for (long idx = (long)blockIdx.x * blockDim.x + threadIdx.x; idx < total;
       idx += (long)gridDim.x * blockDim.x) {
    int k = (int)(idx % Kcat);
    long r = idx / Kcat;
    int b = (int)(r & 63);
    int t = (int)(r >> 6);
    float v;
    if (k < inK) {
      if (layer == 0) v = xin[((long)b * T_DIM + t) * F_DIM + k];
      else v = prev[((long)(t + scale - 1) * B_DIM + b) * H_DIM + k];
    } else {
      int kk = k - inK;
      int t0 = t + scale - 1;
      float s = 0.f;
      for (int w = 0; w < scale; ++w) s += xin[((long)b * T_DIM + t0 + w) * F_DIM + kk];
      v = s * (1.f / scale);
    }
    Abuf[idx] = (_Float16)v;
  }
}

// ---------------------------------------------------------------------------
// f16 MFMA GEMM (unchanged, verified)
// ---------------------------------------------------------------------------
__global__ __launch_bounds__(256) void gemm_f16(const _Float16* __restrict__ A,
                                                const _Float16* __restrict__ Bt,
                                                float* __restrict__ C, int Mrows,
                                                int Kcat) {
  __shared__ _Float16 As[128][72];
  __shared__ _Float16 Bs[128][72];
  const int tid = threadIdx.x;
  const int tn = blockIdx.x, tm = blockIdx.y;
  const int lane = tid & 63, wid = tid >> 6;
  const int wm = wid >> 1, wn = wid & 1;
  f32x4 acc[4][4] = {};
  const int nK = Kcat >> 6;
  const int lrow = tid >> 3, lkc = (tid & 7) * 8;

  for (int kt = 0; kt < nK; ++kt) {
    for (int r = 0; r < 4; ++r) {
      int row = r * 32 + lrow;
      int grow = tm * 128 + row;
      uint4 va = make_uint4(0u, 0u, 0u, 0u);
      if (grow < Mrows) va = *(const uint4*)&A[(size_t)grow * Kcat + kt * 64 + lkc];
      *(uint4*)&As[row][lkc] = va;
      uint4 vb = *(const uint4*)&Bt[(size_t)(tn * 128 + row) * 640 + kt * 64 + lkc];
      *(uint4*)&Bs[row][lkc] = vb;
    }
    __syncthreads();
#pragma unroll
    for (int kk = 0; kk < 64; kk += 32) {
      f16x8 af[4], bf[4];
#pragma unroll
      for (int mt = 0; mt < 4; ++mt)
        af[mt] = *(const f16x8*)&As[wm * 64 + mt * 16 + (lane & 15)][kk + (lane >> 4) * 8];
#pragma unroll
      for (int nt = 0; nt < 4; ++nt)
        bf[nt] = *(const f16x8*)&Bs[wn * 64 + nt * 16 + (lane & 15)][kk + (lane >> 4) * 8];
#pragma unroll
      for (int mt = 0; mt < 4; ++mt)
#pragma unroll
        for (int nt = 0; nt < 4; ++nt)
          acc[mt][nt] = __builtin_amdgcn_mfma_f32_16x16x32_f16(af[mt], bf[nt], acc[mt][nt], 0, 0, 0);
    }
    __syncthreads();
  }

  const int crow0 = tm * 128 + wm * 64 + (lane >> 4) * 4;
  const int ccol0 = tn * 128 + wn * 64 + (lane & 15);
#pragma unroll
  for (int mt = 0; mt < 4; ++mt)
#pragma unroll
    for (int q = 0; q < 4; ++q) {
      int grow = crow0 + mt * 16 + q;
      if (grow < Mrows) {
#pragma unroll
        for (int nt = 0; nt < 4; ++nt)
          C[(size_t)grow * 512 + ccol0 + nt * 16] = acc[mt][nt][q];
      }
    }
}

// ---------------------------------------------------------------------------
// rec_fused v3: swapped-operand MFMA. C[j][b] = whT_tile x h^T, so each lane
// owns batch b = lane&15, rows j in 8 groups of 4 consecutive -> vectorized
// pre/out (dwordx4 x8) and h-writes (ds_write_b64 x8).
// hstage slot(b,j) = (j>>5)*64 + ((j>>3)&3)*16 + (b ^ ((j>>3)&1)):
//   reads 2-way (free), writes conflict-free (verified bank algebra).
// wh: kb 0..11 in VGPR/AGPR (bfr), kb 12..15 in LDS (Blds), LDS-kbs
// interleaved into the reg-kb MFMA stream for read-latency cover.
// One lgkmcnt-only barrier per step.
// ---------------------------------------------------------------------------
__global__ __launch_bounds__(256, 1) void rec_fused(float* __restrict__ po,
                                                    const _Float16* __restrict__ whT,
                                                    int n) {
  const int tid = threadIdx.x;
  const int b0g = blockIdx.x * 16;
  const int lane = tid & 63, wid = tid >> 6;
  const int colbase = wid * 128;  // wave owns cols [128w, 128w+128)
  const int bq = lane & 15;       // batch (C column)
  const int u = lane >> 4;        // k-chunk / j-subrow selector

  __shared__ _Float16 hstage[2][16 * 512];     // 32 KB
  __shared__ _Float16 Blds[4 * 32 * 64 * 8];   // 128 KB, A-frag order kb 12..15

  // one-time: fill Blds (frag-order gather from whT)
  {
    uint4* B4 = (uint4*)Blds;
    for (int p = 0; p < 32; ++p) {
      int flat = p * 256 + tid;          // 0..8191
      int l = flat & 63;
      int gn = (flat >> 6) & 31;
      int kb12 = flat >> 11;             // 0..3
      B4[flat] = *(const uint4*)&whT[(size_t)(gn * 16 + (l & 15)) * 512 +
                                     (kb12 + 12) * 32 + (l >> 4) * 8];
    }
  }
  // one-time: weight A-frags kb 0..11 (8 n-tiles x 12 kb, VGPR+AGPR)
  f16x8 bfr[8][12];
  {
#pragma unroll
    for (int nt = 0; nt < 8; ++nt) {
      const int j = colbase + nt * 16 + bq;
#pragma unroll
      for (int kb = 0; kb < 12; ++kb)
        bfr[nt][kb] = *(const f16x8*)&whT[(size_t)j * 512 + kb * 32 + u * 8];
    }
  }
  __syncthreads();  // Blds ready

  const int gnb = wid * 8;
  // lane's global base: batch row (b0g+bq), col block colbase + u*4
  const size_t base = (size_t)(b0g + bq) * 512 + colbase + u * 4;

  // prefetch pre[0] (nt 0..3 only; nt 4..7 loaded just-in-time)
  f32x4 pf[4];
  {
    const float* p0 = po + base;
#pragma unroll
    for (int i = 0; i < 4; ++i) pf[i] = *(const f32x4*)&p0[i * 16];
  }

  for (int t = 0; t < n; ++t) {
    const float* pc = po + (size_t)t * (B_DIM * H_DIM) + base;
    f32x4 acc[8];
#pragma unroll
    for (int i = 0; i < 4; ++i) acc[i] = pf[i];
#pragma unroll
    for (int nt = 4; nt < 8; ++nt) acc[nt] = *(const f32x4*)&pc[nt * 16];
    // issue prefetch pre[t+1] nt 0..3 (never drained by barrier)
    {
      const int tnx = (t + 1 < n) ? t + 1 : t;
      const float* pn = po + (size_t)tnx * (B_DIM * H_DIM) + base;
#pragma unroll
      for (int i = 0; i < 4; ++i) pf[i] = *(const f32x4*)&pn[i * 16];
    }

    if (t > 0) {
      const _Float16* hs = hstage[(t - 1) & 1];
#define AFRD(kb) (*(const f16x8*)&hs[((kb)*64 + u * 16 + (bq ^ (u & 1))) * 8])
#define BLRD(kb, nt) \
  (*(const f16x8*)&Blds[((((kb)-12) * 32 + gnb + (nt)) * 64 + lane) * 8])
      f16x8 afr[4];
      afr[0] = AFRD(12);
      afr[1] = AFRD(0);
      afr[2] = AFRD(1);
      afr[3] = AFRD(2);
      f16x8 blr[8];
#pragma unroll
      for (int i = 0; i < 8; ++i) blr[i] = BLRD(12, i);
      // LDS-kbs interleaved among reg-kbs: >=4 reg-kbs of MFMA cover per reload
      constexpr int seq[16] = {12, 0, 1, 2, 3, 13, 4, 5, 6, 7, 14, 8, 9, 10, 15, 11};
#pragma unroll
      for (int i = 0; i < 16; ++i) {
        const int kb = seq[i];
        f16x8 a = afr[i & 3];
        if (i + 4 < 16) afr[i & 3] = AFRD(seq[i + 4]);
        if (kb < 12) {
#pragma unroll
          for (int nt = 0; nt < 8; ++nt)
            acc[nt] = __builtin_amdgcn_mfma_f32_16x16x32_f16(bfr[nt][kb], a, acc[nt], 0, 0, 0);
        } else {
#pragma unroll
          for (int nt = 0; nt < 8; ++nt) {
            f16x8 w = blr[nt];
            if (kb < 15) blr[nt] = BLRD(kb + 1, nt);
            acc[nt] = __builtin_amdgcn_mfma_f32_16x16x32_f16(w, a, acc[nt], 0, 0, 0);
          }
        }
      }
#undef AFRD
#undef BLRD
    }

    // tanh; vectorized h16 write (ds_write_b64) + f32 out write (dwordx4)
    _Float16* hw = hstage[t & 1];
    float* pw = po + (size_t)t * (B_DIM * H_DIM) + base;
#pragma unroll
    for (int nt = 0; nt < 8; ++nt) {
      const int J = colbase + nt * 16 + u * 4;
      const int slot = (J >> 5) * 64 + ((J >> 3) & 3) * 16 + (bq ^ ((J >> 3) & 1));
      f16x4 h4;
#pragma unroll
      for (int q = 0; q < 4; ++q) {
        float a = acc[nt][q];
        float e = __builtin_amdgcn_exp2f(a * 2.8853900817779268f);
        float h = 1.f - 2.f * __builtin_amdgcn_rcpf(e + 1.f);
        acc[nt][q] = h;
        h4[q] = (_Float16)h;
      }
      *(f16x4*)&hw[slot * 8 + (J & 7)] = h4;
      *(f32x4*)&pw[nt * 16] = acc[nt];
    }
    // single barrier: drain LDS writes only (no vmcnt drain)
    asm volatile("s_waitcnt lgkmcnt(0)\n\ts_barrier" ::: "memory");
  }
}

// ---------------------------------------------------------------------------
extern "C" void kernel_launch(void* const* d_in, const int* in_sizes, int n_in,
                              void* d_out, int out_size, void* d_ws, size_t ws_size,
                              hipStream_t stream) {
  const float* inputs = (const float*)d_in[0];
  const float* wi[3] = {(const float*)d_in[1], (const float*)d_in[4], (const float*)d_in[7]};
  const float* wsm[3] = {(const float*)d_in[2], (const float*)d_in[5], (const float*)d_in[8]};
  const float* wh[3] = {(const float*)d_in[3], (const float*)d_in[6], (const float*)d_in[9]};
  float* out = (float*)d_out;

  char* wsp = (char*)d_ws;
  _Float16* whT16 = (_Float16*)wsp;                 // 3*512*512*2 = 1,572,864
  _Float16* wcat = (_Float16*)(wsp + 1572864);      // 3*512*640*2 = 1,966,080
  _Float16* Abuf = (_Float16*)(wsp + 3538944);      // 32704*640*2 = 41,861,120

  prep_whT16<<<1024, 256, 0, stream>>>(whT16, wh[0], wh[1], wh[2]);
  prep_wcat<<<1024, 256, 0, stream>>>(wcat, wi[0], wsm[0], wi[1], wsm[1], wi[2], wsm[2]);

  const int nL[3] = {511, 509, 505};
  const long offL[3] = {0L, 511L * 64 * 512, (511L + 509L) * 64 * 512};
  const int inKL[3] = {128, 512, 512};
  const int scaleL[3] = {1, 2, 4};

  for (int l = 0; l < 3; ++l) {
    const int n = nL[l], inK = inKL[l], Kcat = inK + 128;
    const float* prev = (l == 0) ? nullptr : out + offL[l - 1];
    build_A<<<4096, 256, 0, stream>>>(Abuf, inputs, prev, n, inK, scaleL[l], l);
    const int Mrows = n * 64;
    const int Mt = (Mrows + 127) / 128;
    gemm_f16<<<dim3(4, Mt), 256, 0, stream>>>(Abuf, wcat + (size_t)l * 512 * 640,
                                              out + offL[l], Mrows, Kcat);
    rec_fused<<<4, 256, 0, stream>>>(out + offL[l], whT16 + (size_t)l * 262144, n);
  }
}

// Round 6
// 4400.623 us; speedup vs baseline: 1.6523x; 1.0764x over previous
//
#include <hip/hip_runtime.h>

#define T_DIM 512
#define B_DIM 64
#define F_DIM 128
#define H_DIM 512

typedef _Float16 f16x8 __attribute__((ext_vector_type(8)));
typedef _Float16 f16x4 __attribute__((ext_vector_type(4)));
typedef float f32x4 __attribute__((ext_vector_type(4)));

// ---------------------------------------------------------------------------
// prep: whT16[l][j][k] f16  (wh[k][j] transposed, for A-fragment loads)
// ---------------------------------------------------------------------------
__global__ void prep_whT16(_Float16* __restrict__ dst, const float* __restrict__ w0,
                           const float* __restrict__ w1, const float* __restrict__ w2) {
  const long total = 3L * 512 * 512;
  for (long idx = (long)blockIdx.x * blockDim.x + threadIdx.x; idx < total;
       idx += (long)gridDim.x * blockDim.x) {
    int l = (int)(idx >> 18);
    int rem = (int)(idx & 262143);
    int j = rem >> 9, k = rem & 511;
    const float* src = (l == 0) ? w0 : (l == 1) ? w1 : w2;
    dst[idx] = (_Float16)src[k * 512 + j];
  }
}

// ---------------------------------------------------------------------------
// prep: Wcat^T [l][n=512][kc=640] f16
// ---------------------------------------------------------------------------
__global__ void prep_wcat(_Float16* __restrict__ dst,
                          const float* __restrict__ wi0, const float* __restrict__ ws0,
                          const float* __restrict__ wi1, const float* __restrict__ ws1,
                          const float* __restrict__ wi2, const float* __restrict__ ws2) {
  const long total = 3L * 512 * 640;
  for (long idx = (long)blockIdx.x * blockDim.x + threadIdx.x; idx < total;
       idx += (long)gridDim.x * blockDim.x) {
    int l = (int)(idx / 327680);
    int rem = (int)(idx % 327680);
    int n = rem / 640, kc = rem % 640;
    int inK = (l == 0) ? 128 : 512;
    const float* wi = (l == 0) ? wi0 : (l == 1) ? wi1 : wi2;
    const float* ws = (l == 0) ? ws0 : (l == 1) ? ws1 : ws2;
    float v = 0.f;
    if (kc < inK) v = wi[kc * 512 + n];
    else if (kc < inK + 128) v = ws[(kc - inK) * 512 + n];
    dst[idx] = (_Float16)v;
  }
}

// ---------------------------------------------------------------------------
// build A' panel f16 (unchanged, verified)
// ---------------------------------------------------------------------------
__global__ void build_A(_Float16* __restrict__ Abuf, const float* __restrict__ xin,
                        const float* __restrict__ prev, int n, int inK, int scale,
                        int layer) {
  const int Kcat = inK + 128;
  const long total = (long)n * 64 * Kcat;
  for (long idx = (long)blockIdx.x * blockDim.x + threadIdx.x; idx < total;
       idx += (long)gridDim.x * blockDim.x) {
    int k = (int)(idx % Kcat);
    long r = idx / Kcat;
    int b = (int)(r & 63);
    int t = (int)(r >> 6);
    float v;
    if (k < inK) {
      if (layer == 0) v = xin[((long)b * T_DIM + t) * F_DIM + k];
      else v = prev[((long)(t + scale - 1) * B_DIM + b) * H_DIM + k];
    } else {
      int kk = k - inK;
      int t0 = t + scale - 1;
      float s = 0.f;
      for (int w = 0; w < scale; ++w) s += xin[((long)b * T_DIM + t0 + w) * F_DIM + kk];
      v = s * (1.f / scale);
    }
    Abuf[idx] = (_Float16)v;
  }
}

// ---------------------------------------------------------------------------
// f16 MFMA GEMM (unchanged, verified)
// ---------------------------------------------------------------------------
__global__ __launch_bounds__(256) void gemm_f16(const _Float16* __restrict__ A,
                                                const _Float16* __restrict__ Bt,
                                                float* __restrict__ C, int Mrows,
                                                int Kcat) {
  __shared__ _Float16 As[128][72];
  __shared__ _Float16 Bs[128][72];
  const int tid = threadIdx.x;
  const int tn = blockIdx.x, tm = blockIdx.y;
  const int lane = tid & 63, wid = tid >> 6;
  const int wm = wid >> 1, wn = wid & 1;
  f32x4 acc[4][4] = {};
  const int nK = Kcat >> 6;
  const int lrow = tid >> 3, lkc = (tid & 7) * 8;

  for (int kt = 0; kt < nK; ++kt) {
    for (int r = 0; r < 4; ++r) {
      int row = r * 32 + lrow;
      int grow = tm * 128 + row;
      uint4 va = make_uint4(0u, 0u, 0u, 0u);
      if (grow < Mrows) va = *(const uint4*)&A[(size_t)grow * Kcat + kt * 64 + lkc];
      *(uint4*)&As[row][lkc] = va;
      uint4 vb = *(const uint4*)&Bt[(size_t)(tn * 128 + row) * 640 + kt * 64 + lkc];
      *(uint4*)&Bs[row][lkc] = vb;
    }
    __syncthreads();
#pragma unroll
    for (int kk = 0; kk < 64; kk += 32) {
      f16x8 af[4], bf[4];
#pragma unroll
      for (int mt = 0; mt < 4; ++mt)
        af[mt] = *(const f16x8*)&As[wm * 64 + mt * 16 + (lane & 15)][kk + (lane >> 4) * 8];
#pragma unroll
      for (int nt = 0; nt < 4; ++nt)
        bf[nt] = *(const f16x8*)&Bs[wn * 64 + nt * 16 + (lane & 15)][kk + (lane >> 4) * 8];
#pragma unroll
      for (int mt = 0; mt < 4; ++mt)
#pragma unroll
        for (int nt = 0; nt < 4; ++nt)
          acc[mt][nt] = __builtin_amdgcn_mfma_f32_16x16x32_f16(af[mt], bf[nt], acc[mt][nt], 0, 0, 0);
    }
    __syncthreads();
  }

  const int crow0 = tm * 128 + wm * 64 + (lane >> 4) * 4;
  const int ccol0 = tn * 128 + wn * 64 + (lane & 15);
#pragma unroll
  for (int mt = 0; mt < 4; ++mt)
#pragma unroll
    for (int q = 0; q < 4; ++q) {
      int grow = crow0 + mt * 16 + q;
      if (grow < Mrows) {
#pragma unroll
        for (int nt = 0; nt < 4; ++nt)
          C[(size_t)grow * 512 + ccol0 + nt * 16] = acc[mt][nt][q];
      }
    }
}

// ---------------------------------------------------------------------------
// rec_fused v4: 512 threads (8 waves, 2 waves/SIMD for TLP). Wave owns 64
// cols (4 nt). Swapped-operand MFMA C[j][b]; same verified hstage slot map
// and Blds layout as v3. wh kb 0..11 in regs (bfr[4][12]=192), kb 12..15 in
// LDS. One lgkmcnt-only barrier per step. acc loaded directly (no pf regs) —
// partner wave on the SIMD covers the latency.
// ---------------------------------------------------------------------------
__global__ __launch_bounds__(512, 1) void rec_fused(float* __restrict__ po,
                                                    const _Float16* __restrict__ whT,
                                                    int n) {
  const int tid = threadIdx.x;
  const int b0g = blockIdx.x * 16;
  const int lane = tid & 63, wid = tid >> 6;  // wid 0..7
  const int colbase = wid * 64;               // wave owns cols [64w, 64w+64)
  const int bq = lane & 15;                   // batch (C column)
  const int u = lane >> 4;                    // k-chunk / j-subrow selector

  __shared__ _Float16 hstage[2][16 * 512];    // 32 KB
  __shared__ _Float16 Blds[4 * 32 * 64 * 8];  // 128 KB, A-frag order kb 12..15

  // one-time: fill Blds (frag-order gather from whT); 8192 uint4, 512 thr
  {
    uint4* B4 = (uint4*)Blds;
    for (int p = 0; p < 16; ++p) {
      int flat = p * 512 + tid;  // 0..8191
      int l = flat & 63;
      int gn = (flat >> 6) & 31;
      int kb12 = flat >> 11;  // 0..3
      B4[flat] = *(const uint4*)&whT[(size_t)(gn * 16 + (l & 15)) * 512 +
                                     (kb12 + 12) * 32 + (l >> 4) * 8];
    }
  }
  // one-time: weight A-frags kb 0..11 (4 n-tiles x 12 kb = 192 regs)
  f16x8 bfr[4][12];
  {
#pragma unroll
    for (int nt = 0; nt < 4; ++nt) {
      const int j = colbase + nt * 16 + bq;
#pragma unroll
      for (int kb = 0; kb < 12; ++kb)
        bfr[nt][kb] = *(const f16x8*)&whT[(size_t)j * 512 + kb * 32 + u * 8];
    }
  }
  __syncthreads();  // Blds ready

  const int gnb = wid * 4;  // global n-tile base for this wave
  // lane's global base: batch row (b0g+bq), col block colbase + u*4
  const size_t base = (size_t)(b0g + bq) * 512 + colbase + u * 4;

  for (int t = 0; t < n; ++t) {
    const float* pc = po + (size_t)t * (B_DIM * H_DIM) + base;
    f32x4 acc[4];
#pragma unroll
    for (int nt = 0; nt < 4; ++nt) acc[nt] = *(const f32x4*)&pc[nt * 16];

    if (t > 0) {
      const _Float16* hs = hstage[(t - 1) & 1];
#define AFRD(kb) (*(const f16x8*)&hs[((kb)*64 + u * 16 + (bq ^ (u & 1))) * 8])
#define BLRD(kb, nt) \
  (*(const f16x8*)&Blds[((((kb)-12) * 32 + gnb + (nt)) * 64 + lane) * 8])
      f16x8 afr[4];
      afr[0] = AFRD(12);
      afr[1] = AFRD(0);
      afr[2] = AFRD(1);
      afr[3] = AFRD(2);
      f16x8 blr[4];
#pragma unroll
      for (int i = 0; i < 4; ++i) blr[i] = BLRD(12, i);
      // LDS-kbs interleaved among reg-kbs: >=4 reg-kbs of MFMA cover per reload
      constexpr int seq[16] = {12, 0, 1, 2, 3, 13, 4, 5, 6, 7, 14, 8, 9, 10, 15, 11};
#pragma unroll
      for (int i = 0; i < 16; ++i) {
        const int kb = seq[i];
        f16x8 a = afr[i & 3];
        if (i + 4 < 16) afr[i & 3] = AFRD(seq[i + 4]);
        if (kb < 12) {
#pragma unroll
          for (int nt = 0; nt < 4; ++nt)
            acc[nt] = __builtin_amdgcn_mfma_f32_16x16x32_f16(bfr[nt][kb], a, acc[nt], 0, 0, 0);
        } else {
#pragma unroll
          for (int nt = 0; nt < 4; ++nt) {
            f16x8 w = blr[nt];
            if (kb < 15) blr[nt] = BLRD(kb + 1, nt);
            acc[nt] = __builtin_amdgcn_mfma_f32_16x16x32_f16(w, a, acc[nt], 0, 0, 0);
          }
        }
      }
#undef AFRD
#undef BLRD
    }

    // tanh; vectorized h16 write (ds_write_b64) + f32 out write (dwordx4)
    _Float16* hw = hstage[t & 1];
    float* pw = po + (size_t)t * (B_DIM * H_DIM) + base;
#pragma unroll
    for (int nt = 0; nt < 4; ++nt) {
      const int J = colbase + nt * 16 + u * 4;
      const int slot = (J >> 5) * 64 + ((J >> 3) & 3) * 16 + (bq ^ ((J >> 3) & 1));
      f16x4 h4;
#pragma unroll
      for (int q = 0; q < 4; ++q) {
        float a = acc[nt][q];
        float e = __builtin_amdgcn_exp2f(a * 2.8853900817779268f);
        float h = 1.f - 2.f * __builtin_amdgcn_rcpf(e + 1.f);
        acc[nt][q] = h;
        h4[q] = (_Float16)h;
      }
      *(f16x4*)&hw[slot * 8 + (J & 7)] = h4;
      *(f32x4*)&pw[nt * 16] = acc[nt];
    }
    // single barrier: drain LDS writes only (no vmcnt drain)
    asm volatile("s_waitcnt lgkmcnt(0)\n\ts_barrier" ::: "memory");
  }
}

// ---------------------------------------------------------------------------
extern "C" void kernel_launch(void* const* d_in, const int* in_sizes, int n_in,
                              void* d_out, int out_size, void* d_ws, size_t ws_size,
                              hipStream_t stream) {
  const float* inputs = (const float*)d_in[0];
  const float* wi[3] = {(const float*)d_in[1], (const float*)d_in[4], (const float*)d_in[7]};
  const float* wsm[3] = {(const float*)d_in[2], (const float*)d_in[5], (const float*)d_in[8]};
  const float* wh[3] = {(const float*)d_in[3], (const float*)d_in[6], (const float*)d_in[9]};
  float* out = (float*)d_out;

  char* wsp = (char*)d_ws;
  _Float16* whT16 = (_Float16*)wsp;                 // 3*512*512*2 = 1,572,864
  _Float16* wcat = (_Float16*)(wsp + 1572864);      // 3*512*640*2 = 1,966,080
  _Float16* Abuf = (_Float16*)(wsp + 3538944);      // 32704*640*2 = 41,861,120

  prep_whT16<<<1024, 256, 0, stream>>>(whT16, wh[0], wh[1], wh[2]);
  prep_wcat<<<1024, 256, 0, stream>>>(wcat, wi[0], wsm[0], wi[1], wsm[1], wi[2], wsm[2]);

  const int nL[3] = {511, 509, 505};
  const long offL[3] = {0L, 511L * 64 * 512, (511L + 509L) * 64 * 512};
  const int inKL[3] = {128, 512, 512};
  const int scaleL[3] = {1, 2, 4};

  for (int l = 0; l < 3; ++l) {
    const int n = nL[l], inK = inKL[l], Kcat = inK + 128;
    const float* prev = (l == 0) ? nullptr : out + offL[l - 1];
    build_A<<<4096, 256, 0, stream>>>(Abuf, inputs, prev, n, inK, scaleL[l], l);
    const int Mrows = n * 64;
    const int Mt = (Mrows + 127) / 128;
    gemm_f16<<<dim3(4, Mt), 256, 0, stream>>>(Abuf, wcat + (size_t)l * 512 * 640,
                                              out + offL[l], Mrows, Kcat);
    rec_fused<<<4, 512, 0, stream>>>(out + offL[l], whT16 + (size_t)l * 262144, n);
  }
}